// Round 5
// baseline (104.953 us; speedup 1.0000x reference)
//
#include <hip/hip_runtime.h>
#include <math.h>

#define N_NODES 65536
#define G_SEG   512
#define T_ELEMS (300 * 2048)       // T2[zm][j][m]: 300 x 64 x 32 f32 = 2.4 MB
#define NH      8192               // h-table intervals over L in [0,10], nearest-neighbor
#define H_ELEMS ((NH + 1) * 32)    // 262,176 floats = 1.05 MB

// prep kernel block ranges
#define NB_T 1200                      // 300 zm x 4 l
#define NB_H ((H_ELEMS + 255) / 256)   // 1025
#define NB_S 3                         // 513 bounds
#define NB_P0 (N_NODES / 256)          // 256: per-node aux precompute
#define NB_PREP (NB_T + NB_H + NB_S + NB_P0)

// ---------------------------------------------------------------------------
// prep: four independent roles selected by blockIdx.x.
//  role T:  T2[zm][j][m] = (1/sqrt(2048)) * sum_u feat_zm[u] * W2[m][l*1024+u*16+wi]
//  role H:  Htab[e][m] = SILU_C * silu( sum_k basis_k(e*10/NH) * W1[k][m] )   (f64)
//  role S:  seg[g] = lower_bound(batch, g)
//  role P0: aux[i] = (ux, uy, uz, bitcast((e<<9)|zmi))  -- all data-dependent
//           address material hoisted out of the hot kernel
// ---------------------------------------------------------------------------
__global__ __launch_bounds__(256) void prep(
    const float* __restrict__ emb_z, const float* __restrict__ emb_mol,
    const float* __restrict__ W2, const float* __restrict__ W1,
    const int* __restrict__ batch,
    const float* __restrict__ pos, const int* __restrict__ xz,
    const int* __restrict__ mol,
    float* __restrict__ T2, float* __restrict__ Htab, int* __restrict__ seg,
    float4* __restrict__ aux, double silu_c)
{
    const int b = blockIdx.x;
    const int t = threadIdx.x;

    if (b < NB_T) {
        __shared__ float feat[64];
        const int zm = b >> 2;
        const int l  = b & 3;
        const int z  = zm / 3, mo = zm % 3;
        if (t < 48)      feat[t] = emb_z[z * 48 + t];
        else if (t < 64) feat[t] = emb_mol[mo * 16 + (t - 48)];
        __syncthreads();

        const float scale = 0.02209708691207961f;  // 1/sqrt(2048)
        const int wi  = t & 15;
        const int mlo = t >> 4;
#pragma unroll
        for (int i = 0; i < 2; ++i) {
            const int m = mlo + 16 * i;
            const float* w2p = W2 + m * 4096 + l * 1024 + wi;
            float acc = 0.f;
#pragma unroll 8
            for (int u = 0; u < 64; ++u)
                acc = fmaf(feat[u], w2p[u * 16], acc);
            T2[zm * 2048 + (l * 16 + wi) * 32 + m] = acc * scale;
        }
    } else if (b < NB_T + NB_H) {
        const int tid = (b - NB_T) * 256 + t;
        if (tid >= H_ELEMS) return;
        const int e = tid >> 5, m = tid & 31;
        const double L = (double)e * (10.0 / (double)NH);
        const double c = 1.14136 * exp(2.0);
        double p = 0.0;
        for (int k = 0; k < 10; ++k) {
            const double a  = 1.1 * L - (double)k;
            const double bb = (double)(k + 2) - 1.1 * L;
            const double basis = (a > 0.0 && bb > 0.0) ? c * exp(-2.0 / (a * bb)) : 0.0;
            p += basis * (double)W1[k * 32 + m];
        }
        Htab[e * 32 + m] = (float)(silu_c * p / (1.0 + exp(-p)));
    } else if (b < NB_T + NB_H + NB_S) {
        const int g = (b - NB_T - NB_H) * 256 + t;
        if (g > G_SEG) return;
        int lo = 0, hi = N_NODES;
        while (lo < hi) {
            const int mid = (lo + hi) >> 1;
            if (batch[mid] < g) lo = mid + 1; else hi = mid;
        }
        seg[g] = lo;
    } else {
        const int i = (b - NB_T - NB_H - NB_S) * 256 + t;
        const float px = pos[3 * i], py = pos[3 * i + 1], pz = pos[3 * i + 2];
        const int zmi = xz[i] * 3 + mol[i];
        const float Lsq = px * px + py * py + pz * pz;
        const float rinv = __builtin_amdgcn_rsqf(Lsq);
        const float L = Lsq * rinv;
        const float tt = fminf(L * (float)(NH / 10.0) + 0.5f, (float)NH);
        const int e = (int)tt;
        float4 a;
        a.x = px * rinv; a.y = py * rinv; a.z = pz * rinv;
        a.w = __int_as_float((e << 9) | zmi);
        aux[i] = a;
    }
}

// ---------------------------------------------------------------------------
// seg_xw: 4 blocks (256 thr = 4 waves each) per segment quarter. The only
// loads are aux[i] (affine address, prefetchable) and one-dependent-level
// vector loads of hrow/T2 (vmcnt-tracked, in-order -> pipelines). Register
// accumulation, LDS block reduction, pre-scaled by 1/cnt, atomicAdd into
// zeroed out. Lane j = l*16+wi owns output slots [off + wi*(2l+1) .. +2l].
// ---------------------------------------------------------------------------
__global__ __launch_bounds__(256) void seg_xw(
    const float4* __restrict__ aux, const int* __restrict__ seg,
    const float* __restrict__ Htab, const float* __restrict__ T2,
    float* __restrict__ out)
{
    __shared__ float red[4 * 257];

    const int g = blockIdx.x >> 2;
    const int c = blockIdx.x & 3;
    const int s0 = seg[g], s1 = seg[g + 1];
    const int cnt = s1 - s0;
    const int q0 = s0 + ((cnt * c) >> 2);
    const int q1 = s0 + ((cnt * (c + 1)) >> 2);

    const int w    = threadIdx.x >> 6;
    const int lane = threadIdx.x & 63;

    const int l  = lane >> 4;
    const int wi = lane & 15;
    const int nl = 2 * l + 1;
    const int off = (l == 0 ? 0 : (l == 1 ? 16 : (l == 2 ? 64 : 144)));
    const int base = off + wi * nl;

    float acc[7];
#pragma unroll
    for (int k = 0; k < 7; ++k) acc[k] = 0.f;

#pragma unroll 2
    for (int i = q0 + w; i < q1; i += 4) {
        const float4 a = aux[i];                    // broadcast vector load
        const int code = __float_as_int(a.w);
        const int zmi = code & 511;
        const int e   = code >> 9;

        const float4* __restrict__ hp =
            reinterpret_cast<const float4*>(Htab + e * 32);
        const float4* __restrict__ Tp =
            reinterpret_cast<const float4*>(T2 + (size_t)zmi * 2048 + lane * 32);

        float xw0 = 0.f, xw1 = 0.f, xw2 = 0.f, xw3 = 0.f;
#pragma unroll
        for (int q = 0; q < 8; ++q) {
            const float4 h4 = hp[q];                // broadcast (same addr/lane)
            const float4 t4 = Tp[q];                // per-lane 16B
            xw0 = fmaf(h4.x, t4.x, xw0);
            xw1 = fmaf(h4.y, t4.y, xw1);
            xw2 = fmaf(h4.z, t4.z, xw2);
            xw3 = fmaf(h4.w, t4.w, xw3);
        }
        const float xwv = (xw0 + xw1) + (xw2 + xw3);

        // spherical harmonics (component normalization)
        const float ux = a.x, uy = a.y, uz = a.z;
        const float s3 = 1.7320508075688772f, s5 = 2.2360679774997896f, s7 = 2.6457513110645907f;
        const float y2 = uy * uy, x2z2 = ux * ux + uz * uz;
        const float s20 = s3 * ux * uz;
        const float s21 = s3 * ux * uy;
        const float s22 = y2 - 0.5f * x2z2;
        const float s23 = s3 * uy * uz;
        const float s24 = 0.5f * s3 * (uz * uz - ux * ux);

        float shv[7];
#pragma unroll
        for (int k = 0; k < 7; ++k) shv[k] = 0.f;
        if (l == 0) {
            shv[0] = 1.f;
        } else if (l == 1) {
            shv[0] = s3 * ux; shv[1] = s3 * uy; shv[2] = s3 * uz;
        } else if (l == 2) {
            shv[0] = s5 * s20; shv[1] = s5 * s21; shv[2] = s5 * s22;
            shv[3] = s5 * s23; shv[4] = s5 * s24;
        } else {
            const float c56 = 0.9128709291752769f;  // sqrt(5/6)
            const float c38 = 0.6123724356957945f;  // sqrt(3/8)
            const float s30 = c56 * (s20 * uz + s24 * ux);
            const float s31 = s5 * s20 * uy;
            const float s32 = c38 * (4.f * y2 - x2z2) * ux;
            const float s33 = 0.5f * uy * (2.f * y2 - 3.f * x2z2);
            const float s34 = c38 * uz * (4.f * y2 - x2z2);
            const float s35 = s5 * s24 * uy;
            const float s36 = c56 * (s24 * uz - s20 * ux);
            shv[0] = s7 * s30; shv[1] = s7 * s31; shv[2] = s7 * s32;
            shv[3] = s7 * s33; shv[4] = s7 * s34; shv[5] = s7 * s35; shv[6] = s7 * s36;
        }

#pragma unroll
        for (int k = 0; k < 7; ++k)
            if (k < nl) acc[k] = fmaf(xwv, shv[k], acc[k]);
    }

    // block reduction across 4 waves, pre-scaled by 1/cnt, one atomic per slot
#pragma unroll
    for (int k = 0; k < 7; ++k)
        if (k < nl) red[w * 257 + base + k] = acc[k];
    __syncthreads();

    if (threadIdx.x < 256) {
        float s = 0.f;
#pragma unroll
        for (int ww = 0; ww < 4; ++ww) s += red[ww * 257 + threadIdx.x];
        const float inv = 1.f / (float)max(cnt, 1);
        atomicAdd(&out[g * 256 + threadIdx.x], s * inv);
    }
}

// ---------------------------------------------------------------------------
static double silu_c_host()
{
    const int n = 200001;
    const double h = 24.0 / 200000.0;
    double sum = 0.0, prev = 0.0;
    for (int i = 0; i < n; ++i) {
        const double z = -12.0 + h * (double)i;
        const double pdf = exp(-0.5 * z * z) * 0.3989422804014327;
        const double s = z / (1.0 + exp(-z));
        const double f = s * s * pdf;
        if (i) sum += prev + f;
        prev = f;
    }
    sum *= 0.5 * h;
    return 1.0 / sqrt(sum);
}

extern "C" void kernel_launch(void* const* d_in, const int* in_sizes, int n_in,
                              void* d_out, int out_size, void* d_ws, size_t ws_size,
                              hipStream_t stream)
{
    const float* pos     = (const float*)d_in[0];
    const int*   xz      = (const int*)d_in[1];
    const int*   mol     = (const int*)d_in[2];
    const int*   batch   = (const int*)d_in[3];
    const float* emb_z   = (const float*)d_in[4];
    const float* emb_mol = (const float*)d_in[5];
    const float* W1      = (const float*)d_in[6];
    const float* W2      = (const float*)d_in[7];
    float* out = (float*)d_out;

    float*  T2   = (float*)d_ws;                                  // 2.4 MB
    float*  Htab = (float*)d_ws + T_ELEMS;                        // 1.05 MB
    int*    seg  = (int*)((float*)d_ws + T_ELEMS + H_ELEMS);      // 513 ints (pad to 1024)
    float4* aux  = (float4*)((float*)d_ws + T_ELEMS + H_ELEMS + 1024);  // 1 MB

    static const double SILU_C_D = silu_c_host();

    hipMemsetAsync(d_out, 0, (size_t)out_size * sizeof(float), stream);

    prep<<<NB_PREP, 256, 0, stream>>>(emb_z, emb_mol, W2, W1, batch,
                                      pos, xz, mol,
                                      T2, Htab, seg, aux, SILU_C_D);
    seg_xw<<<G_SEG * 4, 256, 0, stream>>>(aux, seg, Htab, T2, out);
}

// Round 6
// 61.925 us; speedup vs baseline: 1.6948x; 1.6948x over previous
//
#include <hip/hip_runtime.h>
#include <math.h>

#define N_NODES 65536
#define G_SEG   512
#define NE      256                 // L-grid intervals over [0,10] for xw lerp
#define T_ELEMS (300 * 2048)        // T2[zm][j][m]: 300 x 64 x 32 f32 = 2.4 MB
#define HS_ELEMS ((NE + 1) * 32)    // 257 x 32 h-grid
#define XW_ELEMS ((NE + 1) * 300 * 64)  // 19.74 MB

// prep roles
#define NB_T  1200                  // 300 zm x 4 l
#define NB_HS ((HS_ELEMS + 255) / 256)  // 33
#define NB_S  3
#define NB_P0 (N_NODES / 256)       // 256
#define NB_PREP (NB_T + NB_HS + NB_S + NB_P0)

#define CH 8                        // chunks per segment in hot kernel

// ---------------------------------------------------------------------------
// prep: four independent roles by blockIdx.x.
//  T:  T2[zm][j][m] = (1/sqrt(2048)) * sum_u feat_zm[u] * W2[m][l*1024+u*16+wi]
//  HS: Hs[e][m] = SILU_C * silu( sum_k basis_k(e*10/NE) * W1[k][m] )  (f64)
//  S:  seg[g] = lower_bound(batch, g)
//  P0: aux[i] = (ux, uy, uz, pack(e, zmi, frac14))
// ---------------------------------------------------------------------------
__global__ __launch_bounds__(256) void prep(
    const float* __restrict__ emb_z, const float* __restrict__ emb_mol,
    const float* __restrict__ W2, const float* __restrict__ W1,
    const int* __restrict__ batch,
    const float* __restrict__ pos, const int* __restrict__ xz,
    const int* __restrict__ mol,
    float* __restrict__ T2, float* __restrict__ Hs, int* __restrict__ seg,
    float4* __restrict__ aux, double silu_c)
{
    const int b = blockIdx.x;
    const int t = threadIdx.x;

    if (b < NB_T) {
        __shared__ float feat[64];
        const int zm = b >> 2;
        const int l  = b & 3;
        const int z  = zm / 3, mo = zm % 3;
        if (t < 48)      feat[t] = emb_z[z * 48 + t];
        else if (t < 64) feat[t] = emb_mol[mo * 16 + (t - 48)];
        __syncthreads();

        const float scale = 0.02209708691207961f;  // 1/sqrt(2048)
        const int wi  = t & 15;
        const int mlo = t >> 4;
#pragma unroll
        for (int i = 0; i < 2; ++i) {
            const int m = mlo + 16 * i;
            const float* w2p = W2 + m * 4096 + l * 1024 + wi;
            float acc = 0.f;
#pragma unroll 8
            for (int u = 0; u < 64; ++u)
                acc = fmaf(feat[u], w2p[u * 16], acc);
            T2[zm * 2048 + (l * 16 + wi) * 32 + m] = acc * scale;
        }
    } else if (b < NB_T + NB_HS) {
        const int tid = (b - NB_T) * 256 + t;
        if (tid >= HS_ELEMS) return;
        const int e = tid >> 5, m = tid & 31;
        const double L = (double)e * (10.0 / (double)NE);
        const double c = 1.14136 * exp(2.0);
        double p = 0.0;
        for (int k = 0; k < 10; ++k) {
            const double a  = 1.1 * L - (double)k;
            const double bb = (double)(k + 2) - 1.1 * L;
            // exp(-1/a)*exp(-1/b) = exp(-2/(ab)) since a+b == 2
            const double basis = (a > 0.0 && bb > 0.0) ? c * exp(-2.0 / (a * bb)) : 0.0;
            p += basis * (double)W1[k * 32 + m];
        }
        Hs[tid] = (float)(silu_c * p / (1.0 + exp(-p)));
    } else if (b < NB_T + NB_HS + NB_S) {
        const int g = (b - NB_T - NB_HS) * 256 + t;
        if (g > G_SEG) return;
        int lo = 0, hi = N_NODES;
        while (lo < hi) {
            const int mid = (lo + hi) >> 1;
            if (batch[mid] < g) lo = mid + 1; else hi = mid;
        }
        seg[g] = lo;
    } else {
        const int i = (b - NB_T - NB_HS - NB_S) * 256 + t;
        const float px = pos[3 * i], py = pos[3 * i + 1], pz = pos[3 * i + 2];
        const int zmi = xz[i] * 3 + mol[i];
        const float Lsq = px * px + py * py + pz * pz;
        const float rinv = __builtin_amdgcn_rsqf(Lsq);
        const float L = Lsq * rinv;
        const float tt = fminf(L * ((float)NE / 10.0f), 255.999f);
        const int e = (int)tt;
        const int fr14 = min((int)((tt - (float)e) * 16384.f), 16383);
        float4 a;
        a.x = px * rinv; a.y = py * rinv; a.z = pz * rinv;
        a.w = __uint_as_float(((unsigned)e << 23) | ((unsigned)zmi << 14) | (unsigned)fr14);
        aux[i] = a;
    }
}

// ---------------------------------------------------------------------------
// build_xw: xwtab[e][zm][j] = sum_m Hs[e][m] * T2[zm][j][m].
// grid (300, 4), 256 thr = 4 waves. Lane j keeps its 32-float T2 row in
// registers; each wave sweeps 16 e-bins (last wave: 17, covering e=256).
// ---------------------------------------------------------------------------
__global__ __launch_bounds__(256) void build_xw(
    const float* __restrict__ T2, const float* __restrict__ Hs,
    float* __restrict__ xwtab)
{
    const int zm = blockIdx.x;
    const int q  = blockIdx.y;
    const int w  = threadIdx.x >> 6;
    const int j  = threadIdx.x & 63;

    float tm[32];
    const float4* __restrict__ Tp =
        reinterpret_cast<const float4*>(T2 + zm * 2048 + j * 32);
#pragma unroll
    for (int s = 0; s < 8; ++s) {
        const float4 v = Tp[s];
        tm[4 * s] = v.x; tm[4 * s + 1] = v.y; tm[4 * s + 2] = v.z; tm[4 * s + 3] = v.w;
    }

    const int e0 = q * 64 + w * 16;
    const int e1 = (q == 3 && w == 3) ? (NE + 1) : (e0 + 16);
    for (int e = e0; e < e1; ++e) {
        const float* __restrict__ hs = Hs + e * 32;   // wave-uniform
        float a0 = 0.f, a1 = 0.f, a2 = 0.f, a3 = 0.f;
#pragma unroll
        for (int m = 0; m < 32; m += 4) {
            a0 = fmaf(hs[m + 0], tm[m + 0], a0);
            a1 = fmaf(hs[m + 1], tm[m + 1], a1);
            a2 = fmaf(hs[m + 2], tm[m + 2], a2);
            a3 = fmaf(hs[m + 3], tm[m + 3], a3);
        }
        xwtab[((e * 300 + zm) << 6) + j] = (a0 + a1) + (a2 + a3);
    }
}

// ---------------------------------------------------------------------------
// seg_xw: CH blocks per segment, 256 thr = 4 waves. Per node: one broadcast
// aux load, TWO 256B lerp-row loads (one dword per lane), ~45 VALU. Register
// accumulation, LDS block reduction, pre-scaled by 1/cnt, atomicAdd into
// zeroed out. Lane j = l*16+wi owns output slots [off + wi*(2l+1) .. +2l].
// ---------------------------------------------------------------------------
__global__ __launch_bounds__(256) void seg_xw(
    const float4* __restrict__ aux, const int* __restrict__ seg,
    const float* __restrict__ xwtab, float* __restrict__ out)
{
    __shared__ float red[4 * 257];

    const int g = blockIdx.x / CH;
    const int c = blockIdx.x % CH;
    const int s0 = seg[g], s1 = seg[g + 1];
    const int cnt = s1 - s0;
    const int q0 = s0 + (cnt * c) / CH;
    const int q1 = s0 + (cnt * (c + 1)) / CH;

    const int w    = threadIdx.x >> 6;
    const int lane = threadIdx.x & 63;

    const int l  = lane >> 4;
    const int wi = lane & 15;
    const int nl = 2 * l + 1;
    const int off = (l == 0 ? 0 : (l == 1 ? 16 : (l == 2 ? 64 : 144)));
    const int base = off + wi * nl;

    float acc[7];
#pragma unroll
    for (int k = 0; k < 7; ++k) acc[k] = 0.f;

#pragma unroll 2
    for (int i = q0 + w; i < q1; i += 4) {
        const float4 a = aux[i];                     // broadcast 16B
        const unsigned code = __float_as_uint(a.w);
        const unsigned e   = code >> 23;
        const unsigned zmi = (code >> 14) & 511u;
        const float fr = (float)(code & 16383u) * 6.103515625e-5f;  // /16384

        const float* __restrict__ r0 = xwtab + (((int)e * 300 + (int)zmi) << 6) + lane;
        const float f0 = r0[0];
        const float f1 = r0[300 * 64];
        const float xwv = fmaf(fr, f1 - f0, f0);

        // spherical harmonics (component normalization)
        const float ux = a.x, uy = a.y, uz = a.z;
        const float s3 = 1.7320508075688772f, s5 = 2.2360679774997896f, s7 = 2.6457513110645907f;
        const float y2 = uy * uy, x2z2 = ux * ux + uz * uz;
        const float s20 = s3 * ux * uz;
        const float s21 = s3 * ux * uy;
        const float s22 = y2 - 0.5f * x2z2;
        const float s23 = s3 * uy * uz;
        const float s24 = 0.5f * s3 * (uz * uz - ux * ux);

        float shv[7];
#pragma unroll
        for (int k = 0; k < 7; ++k) shv[k] = 0.f;
        if (l == 0) {
            shv[0] = 1.f;
        } else if (l == 1) {
            shv[0] = s3 * ux; shv[1] = s3 * uy; shv[2] = s3 * uz;
        } else if (l == 2) {
            shv[0] = s5 * s20; shv[1] = s5 * s21; shv[2] = s5 * s22;
            shv[3] = s5 * s23; shv[4] = s5 * s24;
        } else {
            const float c56 = 0.9128709291752769f;  // sqrt(5/6)
            const float c38 = 0.6123724356957945f;  // sqrt(3/8)
            const float s30 = c56 * (s20 * uz + s24 * ux);
            const float s31 = s5 * s20 * uy;
            const float s32 = c38 * (4.f * y2 - x2z2) * ux;
            const float s33 = 0.5f * uy * (2.f * y2 - 3.f * x2z2);
            const float s34 = c38 * uz * (4.f * y2 - x2z2);
            const float s35 = s5 * s24 * uy;
            const float s36 = c56 * (s24 * uz - s20 * ux);
            shv[0] = s7 * s30; shv[1] = s7 * s31; shv[2] = s7 * s32;
            shv[3] = s7 * s33; shv[4] = s7 * s34; shv[5] = s7 * s35; shv[6] = s7 * s36;
        }

#pragma unroll
        for (int k = 0; k < 7; ++k)
            if (k < nl) acc[k] = fmaf(xwv, shv[k], acc[k]);
    }

    // block reduction across 4 waves, pre-scaled by 1/cnt, one atomic per slot
#pragma unroll
    for (int k = 0; k < 7; ++k)
        if (k < nl) red[w * 257 + base + k] = acc[k];
    __syncthreads();

    if (threadIdx.x < 256) {
        float s = 0.f;
#pragma unroll
        for (int ww = 0; ww < 4; ++ww) s += red[ww * 257 + threadIdx.x];
        const float inv = 1.f / (float)max(cnt, 1);
        atomicAdd(&out[g * 256 + threadIdx.x], s * inv);
    }
}

// ---------------------------------------------------------------------------
static double silu_c_host()
{
    const int n = 200001;
    const double h = 24.0 / 200000.0;
    double sum = 0.0, prev = 0.0;
    for (int i = 0; i < n; ++i) {
        const double z = -12.0 + h * (double)i;
        const double pdf = exp(-0.5 * z * z) * 0.3989422804014327;
        const double s = z / (1.0 + exp(-z));
        const double f = s * s * pdf;
        if (i) sum += prev + f;
        prev = f;
    }
    sum *= 0.5 * h;
    return 1.0 / sqrt(sum);
}

extern "C" void kernel_launch(void* const* d_in, const int* in_sizes, int n_in,
                              void* d_out, int out_size, void* d_ws, size_t ws_size,
                              hipStream_t stream)
{
    const float* pos     = (const float*)d_in[0];
    const int*   xz      = (const int*)d_in[1];
    const int*   mol     = (const int*)d_in[2];
    const int*   batch   = (const int*)d_in[3];
    const float* emb_z   = (const float*)d_in[4];
    const float* emb_mol = (const float*)d_in[5];
    const float* W1      = (const float*)d_in[6];
    const float* W2      = (const float*)d_in[7];
    float* out = (float*)d_out;

    // workspace layout (floats): T2 | Hs | seg(1024 ints) | aux | xwtab  = 23.3 MB
    float*  T2    = (float*)d_ws;
    float*  Hs    = T2 + T_ELEMS;
    int*    seg   = (int*)(Hs + HS_ELEMS + 28);          // pad to 16B boundary
    float4* aux   = (float4*)((float*)seg + 1024);
    float*  xwtab = (float*)aux + 4 * N_NODES;

    static const double SILU_C_D = silu_c_host();

    hipMemsetAsync(d_out, 0, (size_t)out_size * sizeof(float), stream);

    prep<<<NB_PREP, 256, 0, stream>>>(emb_z, emb_mol, W2, W1, batch,
                                      pos, xz, mol, T2, Hs, seg, aux, SILU_C_D);
    dim3 gx(300, 4);
    build_xw<<<gx, 256, 0, stream>>>(T2, Hs, xwtab);
    seg_xw<<<G_SEG * CH, 256, 0, stream>>>(aux, seg, xwtab, out);
}

// Round 7
// 57.239 us; speedup vs baseline: 1.8336x; 1.0819x over previous
//
#include <hip/hip_runtime.h>
#include <math.h>

#define N_NODES 65536
#define G_SEG   512
#define NE      256                 // L-grid intervals over [0,10] for xw lerp
#define T_ELEMS (300 * 2048)        // T2[zm][j][m]: 300 x 64 x 32 f32 = 2.4 MB
#define HS_ELEMS ((NE + 1) * 32)    // 257 x 32 h-grid
#define XW_ELEMS ((NE + 1) * 300 * 64)  // 19.74 MB

// prep roles
#define NB_T  1200                      // 300 zm x 4 l
#define NB_HS ((HS_ELEMS + 255) / 256)  // 33
#define NB_S  3
#define NB_P0 (N_NODES / 256)           // 256: per-node aux precompute
#define NB_Z  (G_SEG * 256 / 1024)      // 128: zero d_out (float4 stores)
#define NB_PREP (NB_T + NB_HS + NB_S + NB_P0 + NB_Z)

#define CH 8                        // chunks per segment in hot kernel

// ---------------------------------------------------------------------------
// prep: five independent roles by blockIdx.x.
//  T:  T2[zm][j][m] = (1/sqrt(2048)) * sum_u feat_zm[u] * W2[m][l*1024+u*16+wi]
//  HS: Hs[e][m] = SILU_C * silu( sum_k basis_k(e*10/NE) * W1[k][m] )  (f64)
//  S:  seg[g] = lower_bound(batch, g)
//  P0: aux[i] = (ux, uy, uz, pack(e, zmi, frac14))
//  Z:  zero d_out (replaces the pathologically slow runtime fillBuffer)
// ---------------------------------------------------------------------------
__global__ __launch_bounds__(256) void prep(
    const float* __restrict__ emb_z, const float* __restrict__ emb_mol,
    const float* __restrict__ W2, const float* __restrict__ W1,
    const int* __restrict__ batch,
    const float* __restrict__ pos, const int* __restrict__ xz,
    const int* __restrict__ mol,
    float* __restrict__ T2, float* __restrict__ Hs, int* __restrict__ seg,
    float4* __restrict__ aux, float4* __restrict__ outz, double silu_c)
{
    const int b = blockIdx.x;
    const int t = threadIdx.x;

    if (b < NB_T) {
        __shared__ float feat[64];
        const int zm = b >> 2;
        const int l  = b & 3;
        const int z  = zm / 3, mo = zm % 3;
        if (t < 48)      feat[t] = emb_z[z * 48 + t];
        else if (t < 64) feat[t] = emb_mol[mo * 16 + (t - 48)];
        __syncthreads();

        const float scale = 0.02209708691207961f;  // 1/sqrt(2048)
        const int wi  = t & 15;
        const int mlo = t >> 4;
#pragma unroll
        for (int i = 0; i < 2; ++i) {
            const int m = mlo + 16 * i;
            const float* w2p = W2 + m * 4096 + l * 1024 + wi;
            float acc = 0.f;
#pragma unroll 8
            for (int u = 0; u < 64; ++u)
                acc = fmaf(feat[u], w2p[u * 16], acc);
            T2[zm * 2048 + (l * 16 + wi) * 32 + m] = acc * scale;
        }
    } else if (b < NB_T + NB_HS) {
        const int tid = (b - NB_T) * 256 + t;
        if (tid >= HS_ELEMS) return;
        const int e = tid >> 5, m = tid & 31;
        const double L = (double)e * (10.0 / (double)NE);
        const double c = 1.14136 * exp(2.0);
        double p = 0.0;
        for (int k = 0; k < 10; ++k) {
            const double a  = 1.1 * L - (double)k;
            const double bb = (double)(k + 2) - 1.1 * L;
            // exp(-1/a)*exp(-1/b) = exp(-2/(ab)) since a+b == 2
            const double basis = (a > 0.0 && bb > 0.0) ? c * exp(-2.0 / (a * bb)) : 0.0;
            p += basis * (double)W1[k * 32 + m];
        }
        Hs[tid] = (float)(silu_c * p / (1.0 + exp(-p)));
    } else if (b < NB_T + NB_HS + NB_S) {
        const int g = (b - NB_T - NB_HS) * 256 + t;
        if (g > G_SEG) return;
        int lo = 0, hi = N_NODES;
        while (lo < hi) {
            const int mid = (lo + hi) >> 1;
            if (batch[mid] < g) lo = mid + 1; else hi = mid;
        }
        seg[g] = lo;
    } else if (b < NB_T + NB_HS + NB_S + NB_P0) {
        const int i = (b - NB_T - NB_HS - NB_S) * 256 + t;
        const float px = pos[3 * i], py = pos[3 * i + 1], pz = pos[3 * i + 2];
        const int zmi = xz[i] * 3 + mol[i];
        const float Lsq = px * px + py * py + pz * pz;
        const float rinv = __builtin_amdgcn_rsqf(Lsq);
        const float L = Lsq * rinv;
        const float tt = fminf(L * ((float)NE / 10.0f), 255.999f);
        const int e = (int)tt;
        const int fr14 = min((int)((tt - (float)e) * 16384.f), 16383);
        float4 a;
        a.x = px * rinv; a.y = py * rinv; a.z = pz * rinv;
        a.w = __uint_as_float(((unsigned)e << 23) | ((unsigned)zmi << 14) | (unsigned)fr14);
        aux[i] = a;
    } else {
        const int i = (b - NB_T - NB_HS - NB_S - NB_P0) * 256 + t;  // float4 index
        outz[i] = make_float4(0.f, 0.f, 0.f, 0.f);
    }
}

// ---------------------------------------------------------------------------
// build_xw: xwtab[e][zm][j] = sum_m Hs[e][m] * T2[zm][j][m].
// grid (300, 4), 256 thr = 4 waves. Lane j keeps its 32-float T2 row in
// registers; each wave sweeps 16 e-bins (last wave: 17, covering e=256).
// ---------------------------------------------------------------------------
__global__ __launch_bounds__(256) void build_xw(
    const float* __restrict__ T2, const float* __restrict__ Hs,
    float* __restrict__ xwtab)
{
    const int zm = blockIdx.x;
    const int q  = blockIdx.y;
    const int w  = threadIdx.x >> 6;
    const int j  = threadIdx.x & 63;

    float tm[32];
    const float4* __restrict__ Tp =
        reinterpret_cast<const float4*>(T2 + zm * 2048 + j * 32);
#pragma unroll
    for (int s = 0; s < 8; ++s) {
        const float4 v = Tp[s];
        tm[4 * s] = v.x; tm[4 * s + 1] = v.y; tm[4 * s + 2] = v.z; tm[4 * s + 3] = v.w;
    }

    const int e0 = q * 64 + w * 16;
    const int e1 = (q == 3 && w == 3) ? (NE + 1) : (e0 + 16);
    for (int e = e0; e < e1; ++e) {
        const float* __restrict__ hs = Hs + e * 32;   // wave-uniform
        float a0 = 0.f, a1 = 0.f, a2 = 0.f, a3 = 0.f;
#pragma unroll
        for (int m = 0; m < 32; m += 4) {
            a0 = fmaf(hs[m + 0], tm[m + 0], a0);
            a1 = fmaf(hs[m + 1], tm[m + 1], a1);
            a2 = fmaf(hs[m + 2], tm[m + 2], a2);
            a3 = fmaf(hs[m + 3], tm[m + 3], a3);
        }
        xwtab[((e * 300 + zm) << 6) + j] = (a0 + a1) + (a2 + a3);
    }
}

// ---------------------------------------------------------------------------
// seg_xw: CH blocks per segment, 256 thr = 4 waves. Per node: one broadcast
// aux load, two 256B lerp-row loads (one dword per lane), ~45 VALU. Register
// accumulation, LDS block reduction, pre-scaled by 1/cnt, atomicAdd into
// zeroed out. Lane j = l*16+wi owns output slots [off + wi*(2l+1) .. +2l].
// ---------------------------------------------------------------------------
__global__ __launch_bounds__(256) void seg_xw(
    const float4* __restrict__ aux, const int* __restrict__ seg,
    const float* __restrict__ xwtab, float* __restrict__ out)
{
    __shared__ float red[4 * 257];

    const int g = blockIdx.x / CH;
    const int c = blockIdx.x % CH;
    const int s0 = seg[g], s1 = seg[g + 1];
    const int cnt = s1 - s0;
    const int q0 = s0 + (cnt * c) / CH;
    const int q1 = s0 + (cnt * (c + 1)) / CH;

    const int w    = threadIdx.x >> 6;
    const int lane = threadIdx.x & 63;

    const int l  = lane >> 4;
    const int wi = lane & 15;
    const int nl = 2 * l + 1;
    const int off = (l == 0 ? 0 : (l == 1 ? 16 : (l == 2 ? 64 : 144)));
    const int base = off + wi * nl;

    float acc[7];
#pragma unroll
    for (int k = 0; k < 7; ++k) acc[k] = 0.f;

#pragma unroll 2
    for (int i = q0 + w; i < q1; i += 4) {
        const float4 a = aux[i];                     // broadcast 16B
        const unsigned code = __float_as_uint(a.w);
        const unsigned e   = code >> 23;
        const unsigned zmi = (code >> 14) & 511u;
        const float fr = (float)(code & 16383u) * 6.103515625e-5f;  // /16384

        const float* __restrict__ r0 = xwtab + (((int)e * 300 + (int)zmi) << 6) + lane;
        const float f0 = r0[0];
        const float f1 = r0[300 * 64];
        const float xwv = fmaf(fr, f1 - f0, f0);

        // spherical harmonics (component normalization)
        const float ux = a.x, uy = a.y, uz = a.z;
        const float s3 = 1.7320508075688772f, s5 = 2.2360679774997896f, s7 = 2.6457513110645907f;
        const float y2 = uy * uy, x2z2 = ux * ux + uz * uz;
        const float s20 = s3 * ux * uz;
        const float s21 = s3 * ux * uy;
        const float s22 = y2 - 0.5f * x2z2;
        const float s23 = s3 * uy * uz;
        const float s24 = 0.5f * s3 * (uz * uz - ux * ux);

        float shv[7];
#pragma unroll
        for (int k = 0; k < 7; ++k) shv[k] = 0.f;
        if (l == 0) {
            shv[0] = 1.f;
        } else if (l == 1) {
            shv[0] = s3 * ux; shv[1] = s3 * uy; shv[2] = s3 * uz;
        } else if (l == 2) {
            shv[0] = s5 * s20; shv[1] = s5 * s21; shv[2] = s5 * s22;
            shv[3] = s5 * s23; shv[4] = s5 * s24;
        } else {
            const float c56 = 0.9128709291752769f;  // sqrt(5/6)
            const float c38 = 0.6123724356957945f;  // sqrt(3/8)
            const float s30 = c56 * (s20 * uz + s24 * ux);
            const float s31 = s5 * s20 * uy;
            const float s32 = c38 * (4.f * y2 - x2z2) * ux;
            const float s33 = 0.5f * uy * (2.f * y2 - 3.f * x2z2);
            const float s34 = c38 * uz * (4.f * y2 - x2z2);
            const float s35 = s5 * s24 * uy;
            const float s36 = c56 * (s24 * uz - s20 * ux);
            shv[0] = s7 * s30; shv[1] = s7 * s31; shv[2] = s7 * s32;
            shv[3] = s7 * s33; shv[4] = s7 * s34; shv[5] = s7 * s35; shv[6] = s7 * s36;
        }

#pragma unroll
        for (int k = 0; k < 7; ++k)
            if (k < nl) acc[k] = fmaf(xwv, shv[k], acc[k]);
    }

    // block reduction across 4 waves, pre-scaled by 1/cnt, one atomic per slot
#pragma unroll
    for (int k = 0; k < 7; ++k)
        if (k < nl) red[w * 257 + base + k] = acc[k];
    __syncthreads();

    if (threadIdx.x < 256) {
        float s = 0.f;
#pragma unroll
        for (int ww = 0; ww < 4; ++ww) s += red[ww * 257 + threadIdx.x];
        const float inv = 1.f / (float)max(cnt, 1);
        atomicAdd(&out[g * 256 + threadIdx.x], s * inv);
    }
}

// ---------------------------------------------------------------------------
static double silu_c_host()
{
    const int n = 200001;
    const double h = 24.0 / 200000.0;
    double sum = 0.0, prev = 0.0;
    for (int i = 0; i < n; ++i) {
        const double z = -12.0 + h * (double)i;
        const double pdf = exp(-0.5 * z * z) * 0.3989422804014327;
        const double s = z / (1.0 + exp(-z));
        const double f = s * s * pdf;
        if (i) sum += prev + f;
        prev = f;
    }
    sum *= 0.5 * h;
    return 1.0 / sqrt(sum);
}

extern "C" void kernel_launch(void* const* d_in, const int* in_sizes, int n_in,
                              void* d_out, int out_size, void* d_ws, size_t ws_size,
                              hipStream_t stream)
{
    const float* pos     = (const float*)d_in[0];
    const int*   xz      = (const int*)d_in[1];
    const int*   mol     = (const int*)d_in[2];
    const int*   batch   = (const int*)d_in[3];
    const float* emb_z   = (const float*)d_in[4];
    const float* emb_mol = (const float*)d_in[5];
    const float* W1      = (const float*)d_in[6];
    const float* W2      = (const float*)d_in[7];
    float* out = (float*)d_out;

    // workspace layout (floats): T2 | Hs | seg(1024 ints) | aux | xwtab  = 23.3 MB
    float*  T2    = (float*)d_ws;
    float*  Hs    = T2 + T_ELEMS;
    int*    seg   = (int*)(Hs + HS_ELEMS + 28);          // pad to 16B boundary
    float4* aux   = (float4*)((float*)seg + 1024);
    float*  xwtab = (float*)aux + 4 * N_NODES;

    static const double SILU_C_D = silu_c_host();

    prep<<<NB_PREP, 256, 0, stream>>>(emb_z, emb_mol, W2, W1, batch,
                                      pos, xz, mol, T2, Hs, seg, aux,
                                      (float4*)out, SILU_C_D);
    dim3 gx(300, 4);
    build_xw<<<gx, 256, 0, stream>>>(T2, Hs, xwtab);
    seg_xw<<<G_SEG * CH, 256, 0, stream>>>(aux, seg, xwtab, out);
}

// Round 8
// 45.186 us; speedup vs baseline: 2.3227x; 1.2667x over previous
//
#include <hip/hip_runtime.h>
#include <math.h>

#define N_NODES 65536
#define G_SEG   512
#define NE      256                 // L-grid intervals over [0,10] for xw lerp
#define T_ELEMS (300 * 2048)        // T2[zm][j][m]: 300 x 64 x 32 f32 = 2.4 MB
#define HS_ELEMS ((NE + 1) * 32)    // 257 x 32 h-grid
#define XW_ELEMS ((NE + 1) * 300 * 64)  // 19.74 MB

// prep roles
#define NB_T  1200                      // 300 zm x 4 l
#define NB_HS ((HS_ELEMS + 255) / 256)  // 33
#define NB_S  3
#define NB_P0 (N_NODES / 256)           // 256: per-node aux precompute
#define NB_PREP (NB_T + NB_HS + NB_S + NB_P0)

#define CH 8                        // chunks per segment in hot kernel

// ---------------------------------------------------------------------------
// prep: four independent roles by blockIdx.x.
//  T:  T2[zm][j][m] = (1/sqrt(2048)) * sum_u feat_zm[u] * W2[m][l*1024+u*16+wi]
//  HS: Hs[e][m] = SILU_C * silu( sum_k basis_k(e*10/NE) * W1[k][m] )  (f64)
//  S:  seg[g] = lower_bound(batch, g)
//  P0: aux[i] = (ux, uy, uz, pack(e, zmi, frac14))
// ---------------------------------------------------------------------------
__global__ __launch_bounds__(256) void prep(
    const float* __restrict__ emb_z, const float* __restrict__ emb_mol,
    const float* __restrict__ W2, const float* __restrict__ W1,
    const int* __restrict__ batch,
    const float* __restrict__ pos, const int* __restrict__ xz,
    const int* __restrict__ mol,
    float* __restrict__ T2, float* __restrict__ Hs, int* __restrict__ seg,
    float4* __restrict__ aux, double silu_c)
{
    const int b = blockIdx.x;
    const int t = threadIdx.x;

    if (b < NB_T) {
        __shared__ float feat[64];
        const int zm = b >> 2;
        const int l  = b & 3;
        const int z  = zm / 3, mo = zm % 3;
        if (t < 48)      feat[t] = emb_z[z * 48 + t];
        else if (t < 64) feat[t] = emb_mol[mo * 16 + (t - 48)];
        __syncthreads();

        const float scale = 0.02209708691207961f;  // 1/sqrt(2048)
        const int wi  = t & 15;
        const int mlo = t >> 4;
#pragma unroll
        for (int i = 0; i < 2; ++i) {
            const int m = mlo + 16 * i;
            const float* w2p = W2 + m * 4096 + l * 1024 + wi;
            float acc = 0.f;
#pragma unroll 8
            for (int u = 0; u < 64; ++u)
                acc = fmaf(feat[u], w2p[u * 16], acc);
            T2[zm * 2048 + (l * 16 + wi) * 32 + m] = acc * scale;
        }
    } else if (b < NB_T + NB_HS) {
        const int tid = (b - NB_T) * 256 + t;
        if (tid >= HS_ELEMS) return;
        const int e = tid >> 5, m = tid & 31;
        const double L = (double)e * (10.0 / (double)NE);
        const double c = 1.14136 * exp(2.0);
        double p = 0.0;
        for (int k = 0; k < 10; ++k) {
            const double a  = 1.1 * L - (double)k;
            const double bb = (double)(k + 2) - 1.1 * L;
            // exp(-1/a)*exp(-1/b) = exp(-2/(ab)) since a+b == 2
            const double basis = (a > 0.0 && bb > 0.0) ? c * exp(-2.0 / (a * bb)) : 0.0;
            p += basis * (double)W1[k * 32 + m];
        }
        Hs[tid] = (float)(silu_c * p / (1.0 + exp(-p)));
    } else if (b < NB_T + NB_HS + NB_S) {
        const int g = (b - NB_T - NB_HS) * 256 + t;
        if (g > G_SEG) return;
        int lo = 0, hi = N_NODES;
        while (lo < hi) {
            const int mid = (lo + hi) >> 1;
            if (batch[mid] < g) lo = mid + 1; else hi = mid;
        }
        seg[g] = lo;
    } else {
        const int i = (b - NB_T - NB_HS - NB_S) * 256 + t;
        const float px = pos[3 * i], py = pos[3 * i + 1], pz = pos[3 * i + 2];
        const int zmi = xz[i] * 3 + mol[i];
        const float Lsq = px * px + py * py + pz * pz;
        const float rinv = __builtin_amdgcn_rsqf(Lsq);
        const float L = Lsq * rinv;
        const float tt = fminf(L * ((float)NE / 10.0f), 255.999f);
        const int e = (int)tt;
        const int fr14 = min((int)((tt - (float)e) * 16384.f), 16383);
        float4 a;
        a.x = px * rinv; a.y = py * rinv; a.z = pz * rinv;
        a.w = __uint_as_float(((unsigned)e << 23) | ((unsigned)zmi << 14) | (unsigned)fr14);
        aux[i] = a;
    }
}

// ---------------------------------------------------------------------------
// build_xw: xwtab[e][zm][j] = sum_m Hs[e][m] * T2[zm][j][m].
// grid (300, 4), 256 thr = 4 waves. Lane j keeps its 32-float T2 row in
// registers; each wave sweeps 16 e-bins (last wave: 17, covering e=256).
// Wave id readfirstlane'd so the hs pointer is provably uniform -> s_loads.
// ---------------------------------------------------------------------------
__global__ __launch_bounds__(256) void build_xw(
    const float* __restrict__ T2, const float* __restrict__ Hs,
    float* __restrict__ xwtab)
{
    const int zm = blockIdx.x;
    const int q  = blockIdx.y;
    const int w  = __builtin_amdgcn_readfirstlane(threadIdx.x >> 6);
    const int j  = threadIdx.x & 63;

    float tm[32];
    const float4* __restrict__ Tp =
        reinterpret_cast<const float4*>(T2 + zm * 2048 + j * 32);
#pragma unroll
    for (int s = 0; s < 8; ++s) {
        const float4 v = Tp[s];
        tm[4 * s] = v.x; tm[4 * s + 1] = v.y; tm[4 * s + 2] = v.z; tm[4 * s + 3] = v.w;
    }

    const int e0 = q * 64 + w * 16;
    const int e1 = (q == 3 && w == 3) ? (NE + 1) : (e0 + 16);
    for (int e = e0; e < e1; ++e) {
        const float* __restrict__ hs = Hs + e * 32;   // wave-uniform
        float a0 = 0.f, a1 = 0.f, a2 = 0.f, a3 = 0.f;
#pragma unroll
        for (int m = 0; m < 32; m += 4) {
            a0 = fmaf(hs[m + 0], tm[m + 0], a0);
            a1 = fmaf(hs[m + 1], tm[m + 1], a1);
            a2 = fmaf(hs[m + 2], tm[m + 2], a2);
            a3 = fmaf(hs[m + 3], tm[m + 3], a3);
        }
        xwtab[((e * 300 + zm) << 6) + j] = (a0 + a1) + (a2 + a3);
    }
}

// ---------------------------------------------------------------------------
// seg_xw: CH blocks per segment, 256 thr = 4 waves. Per node: one broadcast
// aux load, two 256B lerp-row loads, ~45 VALU. Register accumulation, LDS
// block reduction, then a PLAIN coalesced store of the block partial (no
// atomics -- deterministic two-phase reduce).
// Lane j = l*16+wi owns output slots [off + wi*(2l+1) .. +2l].
// ---------------------------------------------------------------------------
__global__ __launch_bounds__(256) void seg_xw(
    const float4* __restrict__ aux, const int* __restrict__ seg,
    const float* __restrict__ xwtab, float* __restrict__ partials)
{
    __shared__ float red[4 * 257];

    const int g = blockIdx.x / CH;
    const int c = blockIdx.x % CH;
    const int s0 = seg[g], s1 = seg[g + 1];
    const int cnt = s1 - s0;
    const int q0 = s0 + (cnt * c) / CH;
    const int q1 = s0 + (cnt * (c + 1)) / CH;

    const int w    = threadIdx.x >> 6;
    const int lane = threadIdx.x & 63;

    const int l  = lane >> 4;
    const int wi = lane & 15;
    const int nl = 2 * l + 1;
    const int off = (l == 0 ? 0 : (l == 1 ? 16 : (l == 2 ? 64 : 144)));
    const int base = off + wi * nl;

    float acc[7];
#pragma unroll
    for (int k = 0; k < 7; ++k) acc[k] = 0.f;

#pragma unroll 2
    for (int i = q0 + w; i < q1; i += 4) {
        const float4 a = aux[i];                     // broadcast 16B
        const unsigned code = __float_as_uint(a.w);
        const unsigned e   = code >> 23;
        const unsigned zmi = (code >> 14) & 511u;
        const float fr = (float)(code & 16383u) * 6.103515625e-5f;  // /16384

        const float* __restrict__ r0 = xwtab + (((int)e * 300 + (int)zmi) << 6) + lane;
        const float f0 = r0[0];
        const float f1 = r0[300 * 64];
        const float xwv = fmaf(fr, f1 - f0, f0);

        // spherical harmonics (component normalization)
        const float ux = a.x, uy = a.y, uz = a.z;
        const float s3 = 1.7320508075688772f, s5 = 2.2360679774997896f, s7 = 2.6457513110645907f;
        const float y2 = uy * uy, x2z2 = ux * ux + uz * uz;
        const float s20 = s3 * ux * uz;
        const float s21 = s3 * ux * uy;
        const float s22 = y2 - 0.5f * x2z2;
        const float s23 = s3 * uy * uz;
        const float s24 = 0.5f * s3 * (uz * uz - ux * ux);

        float shv[7];
#pragma unroll
        for (int k = 0; k < 7; ++k) shv[k] = 0.f;
        if (l == 0) {
            shv[0] = 1.f;
        } else if (l == 1) {
            shv[0] = s3 * ux; shv[1] = s3 * uy; shv[2] = s3 * uz;
        } else if (l == 2) {
            shv[0] = s5 * s20; shv[1] = s5 * s21; shv[2] = s5 * s22;
            shv[3] = s5 * s23; shv[4] = s5 * s24;
        } else {
            const float c56 = 0.9128709291752769f;  // sqrt(5/6)
            const float c38 = 0.6123724356957945f;  // sqrt(3/8)
            const float s30 = c56 * (s20 * uz + s24 * ux);
            const float s31 = s5 * s20 * uy;
            const float s32 = c38 * (4.f * y2 - x2z2) * ux;
            const float s33 = 0.5f * uy * (2.f * y2 - 3.f * x2z2);
            const float s34 = c38 * uz * (4.f * y2 - x2z2);
            const float s35 = s5 * s24 * uy;
            const float s36 = c56 * (s24 * uz - s20 * ux);
            shv[0] = s7 * s30; shv[1] = s7 * s31; shv[2] = s7 * s32;
            shv[3] = s7 * s33; shv[4] = s7 * s34; shv[5] = s7 * s35; shv[6] = s7 * s36;
        }

#pragma unroll
        for (int k = 0; k < 7; ++k)
            if (k < nl) acc[k] = fmaf(xwv, shv[k], acc[k]);
    }

    // block reduction across 4 waves, then one plain coalesced partial store
#pragma unroll
    for (int k = 0; k < 7; ++k)
        if (k < nl) red[w * 257 + base + k] = acc[k];
    __syncthreads();

    if (threadIdx.x < 256) {
        float s = 0.f;
#pragma unroll
        for (int ww = 0; ww < 4; ++ww) s += red[ww * 257 + threadIdx.x];
        partials[blockIdx.x * 256 + threadIdx.x] = s;
    }
}

// ---------------------------------------------------------------------------
// reduce: out[g][t] = (1/cnt) * sum_c partials[g*CH+c][t]
// ---------------------------------------------------------------------------
__global__ __launch_bounds__(256) void reduce(
    const float* __restrict__ partials, const int* __restrict__ seg,
    float* __restrict__ out)
{
    const int g = blockIdx.x;
    const int t = threadIdx.x;
    const int cnt = seg[g + 1] - seg[g];
    float s = 0.f;
#pragma unroll
    for (int c = 0; c < CH; ++c)
        s += partials[(g * CH + c) * 256 + t];
    out[g * 256 + t] = s / (float)max(cnt, 1);
}

// ---------------------------------------------------------------------------
static double silu_c_host()
{
    const int n = 200001;
    const double h = 24.0 / 200000.0;
    double sum = 0.0, prev = 0.0;
    for (int i = 0; i < n; ++i) {
        const double z = -12.0 + h * (double)i;
        const double pdf = exp(-0.5 * z * z) * 0.3989422804014327;
        const double s = z / (1.0 + exp(-z));
        const double f = s * s * pdf;
        if (i) sum += prev + f;
        prev = f;
    }
    sum *= 0.5 * h;
    return 1.0 / sqrt(sum);
}

extern "C" void kernel_launch(void* const* d_in, const int* in_sizes, int n_in,
                              void* d_out, int out_size, void* d_ws, size_t ws_size,
                              hipStream_t stream)
{
    const float* pos     = (const float*)d_in[0];
    const int*   xz      = (const int*)d_in[1];
    const int*   mol     = (const int*)d_in[2];
    const int*   batch   = (const int*)d_in[3];
    const float* emb_z   = (const float*)d_in[4];
    const float* emb_mol = (const float*)d_in[5];
    const float* W1      = (const float*)d_in[6];
    const float* W2      = (const float*)d_in[7];
    float* out = (float*)d_out;

    // workspace layout (floats): T2 | Hs | seg | aux | xwtab | partials ~= 27.3 MB
    float*  T2    = (float*)d_ws;
    float*  Hs    = T2 + T_ELEMS;
    int*    seg   = (int*)(Hs + HS_ELEMS + 28);          // pad to 16B boundary
    float4* aux   = (float4*)((float*)seg + 1024);
    float*  xwtab = (float*)aux + 4 * N_NODES;
    float*  parts = xwtab + XW_ELEMS;                    // 512*CH*256 floats = 4 MB

    static const double SILU_C_D = silu_c_host();

    prep<<<NB_PREP, 256, 0, stream>>>(emb_z, emb_mol, W2, W1, batch,
                                      pos, xz, mol, T2, Hs, seg, aux, SILU_C_D);
    dim3 gx(300, 4);
    build_xw<<<gx, 256, 0, stream>>>(T2, Hs, xwtab);
    seg_xw<<<G_SEG * CH, 256, 0, stream>>>(aux, seg, xwtab, parts);
    reduce<<<G_SEG, 256, 0, stream>>>(parts, seg, out);
}